// Round 3
// baseline (822.484 us; speedup 1.0000x reference)
//
#include <hip/hip_runtime.h>
#include <stdint.h>

#define NN 100000
#define DIM 128
#define RR 8
#define BB 4
#define EE 1600000
#define EPR 200000
#define RN (RR * NN)   // 800000 segments
#define KK (RR * DIM)  // 1024 = GEMM K
#define SLOPE 0.2f

typedef __attribute__((ext_vector_type(8))) short short8;
typedef __attribute__((ext_vector_type(4))) float f32x4;

__device__ __forceinline__ unsigned short f2bf(float f) {
    unsigned u = __float_as_uint(f);
    unsigned r = (u + 0x7FFFu + ((u >> 16) & 1u)) >> 16;  // RNE
    return (unsigned short)r;
}
__device__ __forceinline__ unsigned fkey(float f) {
    unsigned b = __float_as_uint(f);
    return (b & 0x80000000u) ? ~b : (b | 0x80000000u);
}
__device__ __forceinline__ float funkey(unsigned k) {
    unsigned b = (k & 0x80000000u) ? (k & 0x7FFFFFFFu) : ~k;
    return __uint_as_float(b);
}

// --- 1. W[r]=sum_b att[r,b]basis[b]; store stacked-transposed WT[o][r*128+i] bf16;
//        fold attention vectors so edge scores never need Wh.
__global__ void k_prep(const float* __restrict__ att, const float* __restrict__ basis,
                       const float* __restrict__ attention,
                       unsigned short* __restrict__ wtt, float* __restrict__ wsrc,
                       float* __restrict__ wdst) {
    int r = blockIdx.x;
    int i = threadIdx.x;  // 0..127
    float a[BB];
#pragma unroll
    for (int b = 0; b < BB; ++b) a[b] = att[r * BB + b];
    const float* asrc = attention + r * 2 * DIM;
    const float* adst = asrc + DIM;
    float ws = 0.f, wd = 0.f;
    for (int o = 0; o < DIM; ++o) {
        float w = 0.f;
#pragma unroll
        for (int b = 0; b < BB; ++b) w += a[b] * basis[(b * DIM + i) * DIM + o];
        wtt[(size_t)o * KK + r * DIM + i] = f2bf(w);  // WT[o][k], k=r*128+i
        ws += w * asrc[o];
        wd += w * adst[o];
    }
    wsrc[r * DIM + i] = ws;
    wdst[r * DIM + i] = wd;
}

// --- 2. scores s_src/s_dst (f32) + X -> bf16. One wave per node.
__global__ __launch_bounds__(256) void k_scores(const float* __restrict__ x,
        const float* __restrict__ wsrc, const float* __restrict__ wdst,
        float* __restrict__ ssrc, float* __restrict__ sdst, unsigned* __restrict__ xb) {
    __shared__ float sw[2 * RR * DIM];
    for (int t = threadIdx.x; t < RR * DIM; t += 256) {
        sw[t] = wsrc[t];
        sw[RR * DIM + t] = wdst[t];
    }
    __syncthreads();
    int wave = threadIdx.x >> 6, lane = threadIdx.x & 63;
    int n = blockIdx.x * 4 + wave;
    float2 xv = *(const float2*)(x + (size_t)n * DIM + lane * 2);
    xb[n * 64 + lane] = (unsigned)f2bf(xv.x) | ((unsigned)f2bf(xv.y) << 16);
#pragma unroll
    for (int r = 0; r < RR; ++r) {
        float ps = xv.x * sw[r * DIM + 2 * lane] + xv.y * sw[r * DIM + 2 * lane + 1];
        float pd = xv.x * sw[RR * DIM + r * DIM + 2 * lane] +
                   xv.y * sw[RR * DIM + r * DIM + 2 * lane + 1];
#pragma unroll
        for (int o = 32; o > 0; o >>= 1) {
            ps += __shfl_xor(ps, o);
            pd += __shfl_xor(pd, o);
        }
        if (lane == 0) { ssrc[r * NN + n] = ps; sdst[r * NN + n] = pd; }
    }
}

// --- 3. per-edge raw score + per-SEGMENT max + per-SEGMENT degree count
__global__ void k_edge_a(const int* __restrict__ tri, const float* __restrict__ ssrc,
        const float* __restrict__ sdst, float* __restrict__ eraw,
        unsigned* __restrict__ umax, int* __restrict__ cnt) {
    int e = blockIdx.x * 256 + threadIdx.x;
    int src = tri[3 * e], dst = tri[3 * e + 2];
    int rel = e / EPR;
    int seg = rel * NN + dst;
    float er = ssrc[rel * NN + src] + sdst[seg];
    er = er > 0.f ? er : SLOPE * er;
    eraw[e] = er;
    atomicMax(&umax[seg], fkey(er));
    atomicAdd(&cnt[seg], 1);
}

// --- 4. scan over RN=800000 segment counts -> CSR row starts
__global__ void k_scan1(const int* __restrict__ cnt, int* __restrict__ excl,
                        int* __restrict__ bsum, int n) {
    __shared__ int s[256];
    int t = threadIdx.x;
    int base = blockIdx.x * 1024 + t * 4;
    int c[4];
    int sum = 0;
#pragma unroll
    for (int j = 0; j < 4; ++j) { c[j] = (base + j < n) ? cnt[base + j] : 0; sum += c[j]; }
    s[t] = sum;
    __syncthreads();
    for (int off = 1; off < 256; off <<= 1) {
        int u = t >= off ? s[t - off] : 0;
        __syncthreads();
        s[t] += u;
        __syncthreads();
    }
    int run = s[t] - sum;
#pragma unroll
    for (int j = 0; j < 4; ++j) {
        if (base + j < n) excl[base + j] = run;
        run += c[j];
    }
    if (t == 255) bsum[blockIdx.x] = s[255];
}
__global__ void k_scan2(int* bsum, int nb) {
    __shared__ int s[1024];
    int t = threadIdx.x;
    int v = t < nb ? bsum[t] : 0;
    s[t] = v;
    __syncthreads();
    for (int off = 1; off < 1024; off <<= 1) {
        int u = t >= off ? s[t - off] : 0;
        __syncthreads();
        s[t] += u;
        __syncthreads();
    }
    if (t < nb) bsum[t] = s[t] - v;
}
__global__ void k_scan3(int* __restrict__ rowst, const int* __restrict__ bsum,
                        int* __restrict__ cursor, int n) {
    int i = blockIdx.x * 256 + threadIdx.x;
    if (i < n) {
        int v = rowst[i] + bsum[i >> 10];
        rowst[i] = v;
        cursor[i] = v;
    }
}

// --- 5. exp + denom + seg-CSR scatter (src and e_exp)
__global__ void k_edge_b(const int* __restrict__ tri, const float* __restrict__ eraw,
        const unsigned* __restrict__ umax, float* __restrict__ denom,
        int* __restrict__ cursor, int* __restrict__ pmeta, float* __restrict__ pp) {
    int e = blockIdx.x * 256 + threadIdx.x;
    int src = tri[3 * e], dst = tri[3 * e + 2];
    int rel = e / EPR;
    int seg = rel * NN + dst;
    float p = __expf(eraw[e] - funkey(umax[seg]));
    atomicAdd(&denom[seg], p);
    int pos = atomicAdd(&cursor[seg], 1);
    pmeta[pos] = src;
    pp[pos] = p;
}

// --- 6. fused aggregate-in-x-space + GEMM [32 x 1024] @ WT^T + bias + residual.
// Block: 256 thr (4 waves), owns 32 dst rows. A-tile 32x1024 bf16 in LDS,
// XOR-swizzled (16B-granule) to kill ds_read_b128 bank conflicts.
__global__ __launch_bounds__(256) void k_fused(const int* __restrict__ rowst,
        const int* __restrict__ cnt, const int* __restrict__ pmeta,
        const float* __restrict__ pp, const float* __restrict__ denom,
        const uint4* __restrict__ xbv, const unsigned short* __restrict__ wtt,
        const float* __restrict__ x, const float* __restrict__ bias,
        float* __restrict__ out) {
    __shared__ unsigned short atile[32 * 1024];  // 64KB, row stride 2048B
    char* ab = (char*)atile;
    int d0 = blockIdx.x * 32;
    int wave = threadIdx.x >> 6, lane = threadIdx.x & 63;
    int g = lane >> 4, j16 = lane & 15;

    // ---- build phase: 16 rounds x 4 segments/wave (16 lanes each) ----
    for (int q = 0; q < 16; ++q) {
        int sl = (wave << 6) + (q << 2) + g;  // 0..255
        int dl = sl >> 3, r = sl & 7;
        int seg = r * NN + d0 + dl;
        int start = rowst[seg];
        int c = cnt[seg];
        float invd = 1.f / fmaxf(denom[seg], 1e-8f);
        float a[8];
#pragma unroll
        for (int t = 0; t < 8; ++t) a[t] = 0.f;
        for (int j0 = 0; j0 < c; j0 += 8) {
#pragma unroll
            for (int j = 0; j < 8; ++j) {
                if (j0 + j < c) {  // uniform within the 16-lane group
                    int src = pmeta[start + j0 + j];
                    float al = pp[start + j0 + j] * invd;
                    uint4 w = xbv[(size_t)src * 16 + j16];
                    a[0] = fmaf(al, __uint_as_float(w.x << 16), a[0]);
                    a[1] = fmaf(al, __uint_as_float(w.x & 0xFFFF0000u), a[1]);
                    a[2] = fmaf(al, __uint_as_float(w.y << 16), a[2]);
                    a[3] = fmaf(al, __uint_as_float(w.y & 0xFFFF0000u), a[3]);
                    a[4] = fmaf(al, __uint_as_float(w.z << 16), a[4]);
                    a[5] = fmaf(al, __uint_as_float(w.z & 0xFFFF0000u), a[5]);
                    a[6] = fmaf(al, __uint_as_float(w.w << 16), a[6]);
                    a[7] = fmaf(al, __uint_as_float(w.w & 0xFFFF0000u), a[7]);
                }
            }
        }
        uint4 o;
        o.x = (unsigned)f2bf(a[0]) | ((unsigned)f2bf(a[1]) << 16);
        o.y = (unsigned)f2bf(a[2]) | ((unsigned)f2bf(a[3]) << 16);
        o.z = (unsigned)f2bf(a[4]) | ((unsigned)f2bf(a[5]) << 16);
        o.w = (unsigned)f2bf(a[6]) | ((unsigned)f2bf(a[7]) << 16);
        // elem16 index within row = r*16 + j16; XOR low 3 bits with row key
        *(uint4*)(ab + dl * 2048 + (((r * 16 + j16) ^ (dl & 7)) << 4)) = o;
    }
    __syncthreads();

    // ---- GEMM phase: C[32 x 128] = A[32 x 1024] * B[1024 x 128] ----
    // wave owns n-cols [wave*32, wave*32+32). B[k][n] = WT[n][k].
    int m0 = lane & 15;          // A row within m-tile
    int key = m0 & 7;
    f32x4 acc[2][2];
#pragma unroll
    for (int m = 0; m < 2; ++m)
#pragma unroll
        for (int n = 0; n < 2; ++n) acc[m][n] = (f32x4){0.f, 0.f, 0.f, 0.f};
    const unsigned short* b0p = wtt + (size_t)(wave * 32 + m0) * KK + g * 8;
    const unsigned short* b1p = b0p + (size_t)16 * KK;
#pragma unroll 8
    for (int ks = 0; ks < 32; ++ks) {
        int e16 = ks * 4 + g;
        short8 a0 = *(const short8*)(ab + m0 * 2048 + ((e16 ^ key) << 4));
        short8 a1 = *(const short8*)(ab + (16 + m0) * 2048 + ((e16 ^ key) << 4));
        short8 b0 = *(const short8*)(b0p + ks * 32);
        short8 b1 = *(const short8*)(b1p + ks * 32);
        acc[0][0] = __builtin_amdgcn_mfma_f32_16x16x32_bf16(a0, b0, acc[0][0], 0, 0, 0);
        acc[0][1] = __builtin_amdgcn_mfma_f32_16x16x32_bf16(a0, b1, acc[0][1], 0, 0, 0);
        acc[1][0] = __builtin_amdgcn_mfma_f32_16x16x32_bf16(a1, b0, acc[1][0], 0, 0, 0);
        acc[1][1] = __builtin_amdgcn_mfma_f32_16x16x32_bf16(a1, b1, acc[1][1], 0, 0, 0);
    }
    // epilogue: out = acc + x + bias.  C layout: row=(lane>>4)*4+j, col=lane&15
#pragma unroll
    for (int m = 0; m < 2; ++m)
#pragma unroll
        for (int n = 0; n < 2; ++n) {
            int o = wave * 32 + n * 16 + (lane & 15);
            float bv = bias[o];
#pragma unroll
            for (int j = 0; j < 4; ++j) {
                int dl = m * 16 + g * 4 + j;
                size_t idx = (size_t)(d0 + dl) * DIM + o;
                out[idx] = acc[m][n][j] + x[idx] + bv;
            }
        }
}

extern "C" void kernel_launch(void* const* d_in, const int* in_sizes, int n_in,
                              void* d_out, int out_size, void* d_ws, size_t ws_size,
                              hipStream_t stream) {
    const float* x = (const float*)d_in[0];
    const int* tri = (const int*)d_in[1];
    const float* basis = (const float*)d_in[3];
    const float* att = (const float*)d_in[4];
    const float* attention = (const float*)d_in[5];
    const float* bias = (const float*)d_in[6];
    float* out = (float*)d_out;

    char* ws = (char*)d_ws;
    size_t off = 0;
    auto alloc = [&](size_t b) {
        char* p = ws + off;
        off = (off + b + 255) & ~(size_t)255;
        return p;
    };
    unsigned* xb = (unsigned*)alloc((size_t)NN * DIM * 2);              // 25.6 MB
    unsigned short* wtt = (unsigned short*)alloc((size_t)DIM * KK * 2); // 256 KB
    float* wsrc = (float*)alloc(RR * DIM * 4);
    float* wdst = (float*)alloc(RR * DIM * 4);
    float* ssrc = (float*)alloc((size_t)RR * NN * 4);
    float* sdst = (float*)alloc((size_t)RR * NN * 4);
    float* eraw = (float*)alloc((size_t)EE * 4);
    unsigned* umax = (unsigned*)alloc((size_t)RN * 4);
    float* denom = (float*)alloc((size_t)RN * 4);
    int* cnt = (int*)alloc((size_t)RN * 4);
    int* rowst = (int*)alloc((size_t)RN * 4);
    int* cursor = (int*)alloc((size_t)RN * 4);
    int* bsum = (int*)alloc(4096);
    int* pmeta = (int*)alloc((size_t)EE * 4);
    float* pp = (float*)alloc((size_t)EE * 4);

    (void)hipMemsetAsync(umax, 0, (size_t)RN * 4, stream);
    (void)hipMemsetAsync(denom, 0, (size_t)RN * 4, stream);
    (void)hipMemsetAsync(cnt, 0, (size_t)RN * 4, stream);

    k_prep<<<RR, DIM, 0, stream>>>(att, basis, attention, wtt, wsrc, wdst);
    k_scores<<<NN / 4, 256, 0, stream>>>(x, wsrc, wdst, ssrc, sdst, xb);
    k_edge_a<<<EE / 256, 256, 0, stream>>>(tri, ssrc, sdst, eraw, umax, cnt);
    int nb = (RN + 1023) / 1024;  // 782
    k_scan1<<<nb, 256, 0, stream>>>(cnt, rowst, bsum, RN);
    k_scan2<<<1, 1024, 0, stream>>>(bsum, nb);
    k_scan3<<<(RN + 255) / 256, 256, 0, stream>>>(rowst, bsum, cursor, RN);
    k_edge_b<<<EE / 256, 256, 0, stream>>>(tri, eraw, umax, denom, cursor, pmeta, pp);
    k_fused<<<NN / 32, 256, 0, stream>>>(rowst, cnt, pmeta, pp, denom,
                                         (const uint4*)xb, wtt, x, bias, out);
}

// Round 4
// 754.501 us; speedup vs baseline: 1.0901x; 1.0901x over previous
//
#include <hip/hip_runtime.h>
#include <stdint.h>

#define NN 100000
#define DIM 128
#define RR 8
#define BB 4
#define EE 1600000
#define EPR 200000
#define RN (RR * NN)   // 800000 segments
#define KK (RR * DIM)  // 1024 = GEMM K
#define SLOPE 0.2f

typedef __attribute__((ext_vector_type(8))) short short8;
typedef __attribute__((ext_vector_type(4))) float f32x4;

__device__ __forceinline__ unsigned short f2bf(float f) {
    unsigned u = __float_as_uint(f);
    unsigned r = (u + 0x7FFFu + ((u >> 16) & 1u)) >> 16;  // RNE
    return (unsigned short)r;
}
__device__ __forceinline__ unsigned fkey(float f) {
    unsigned b = __float_as_uint(f);
    return (b & 0x80000000u) ? ~b : (b | 0x80000000u);
}
__device__ __forceinline__ float funkey(unsigned k) {
    unsigned b = (k & 0x80000000u) ? (k & 0x7FFFFFFFu) : ~k;
    return __uint_as_float(b);
}

// --- 1. W[r]=sum_b att[r,b]basis[b]; store stacked-transposed WT[o][r*128+i] bf16;
//        fold attention vectors so edge scores never need Wh.
__global__ void k_prep(const float* __restrict__ att, const float* __restrict__ basis,
                       const float* __restrict__ attention,
                       unsigned short* __restrict__ wtt, float* __restrict__ wsrc,
                       float* __restrict__ wdst) {
    int r = blockIdx.x;
    int i = threadIdx.x;  // 0..127
    float a[BB];
#pragma unroll
    for (int b = 0; b < BB; ++b) a[b] = att[r * BB + b];
    const float* asrc = attention + r * 2 * DIM;
    const float* adst = asrc + DIM;
    float ws = 0.f, wd = 0.f;
    for (int o = 0; o < DIM; ++o) {
        float w = 0.f;
#pragma unroll
        for (int b = 0; b < BB; ++b) w += a[b] * basis[(b * DIM + i) * DIM + o];
        wtt[(size_t)o * KK + r * DIM + i] = f2bf(w);  // WT[o][k], k=r*128+i
        ws += w * asrc[o];
        wd += w * adst[o];
    }
    wsrc[r * DIM + i] = ws;
    wdst[r * DIM + i] = wd;
}

// --- 2. scores s_src/s_dst (f32) + X -> bf16. One wave per node.
__global__ __launch_bounds__(256) void k_scores(const float* __restrict__ x,
        const float* __restrict__ wsrc, const float* __restrict__ wdst,
        float* __restrict__ ssrc, float* __restrict__ sdst, unsigned* __restrict__ xb) {
    __shared__ float sw[2 * RR * DIM];
    for (int t = threadIdx.x; t < RR * DIM; t += 256) {
        sw[t] = wsrc[t];
        sw[RR * DIM + t] = wdst[t];
    }
    __syncthreads();
    int wave = threadIdx.x >> 6, lane = threadIdx.x & 63;
    int n = blockIdx.x * 4 + wave;
    float2 xv = *(const float2*)(x + (size_t)n * DIM + lane * 2);
    xb[n * 64 + lane] = (unsigned)f2bf(xv.x) | ((unsigned)f2bf(xv.y) << 16);
#pragma unroll
    for (int r = 0; r < RR; ++r) {
        float ps = xv.x * sw[r * DIM + 2 * lane] + xv.y * sw[r * DIM + 2 * lane + 1];
        float pd = xv.x * sw[RR * DIM + r * DIM + 2 * lane] +
                   xv.y * sw[RR * DIM + r * DIM + 2 * lane + 1];
#pragma unroll
        for (int o = 32; o > 0; o >>= 1) {
            ps += __shfl_xor(ps, o);
            pd += __shfl_xor(pd, o);
        }
        if (lane == 0) { ssrc[r * NN + n] = ps; sdst[r * NN + n] = pd; }
    }
}

// --- 3. per-edge raw score + per-SEGMENT max + per-SEGMENT degree count
__global__ void k_edge_a(const int* __restrict__ tri, const float* __restrict__ ssrc,
        const float* __restrict__ sdst, float* __restrict__ eraw,
        unsigned* __restrict__ umax, int* __restrict__ cnt) {
    int e = blockIdx.x * 256 + threadIdx.x;
    int src = tri[3 * e], dst = tri[3 * e + 2];
    int rel = e / EPR;
    int seg = rel * NN + dst;
    float er = ssrc[rel * NN + src] + sdst[seg];
    er = er > 0.f ? er : SLOPE * er;
    eraw[e] = er;
    atomicMax(&umax[seg], fkey(er));
    atomicAdd(&cnt[seg], 1);
}

// --- 4. scan over RN=800000 segment counts -> CSR row starts
__global__ void k_scan1(const int* __restrict__ cnt, int* __restrict__ excl,
                        int* __restrict__ bsum, int n) {
    __shared__ int s[256];
    int t = threadIdx.x;
    int base = blockIdx.x * 1024 + t * 4;
    int c[4];
    int sum = 0;
#pragma unroll
    for (int j = 0; j < 4; ++j) { c[j] = (base + j < n) ? cnt[base + j] : 0; sum += c[j]; }
    s[t] = sum;
    __syncthreads();
    for (int off = 1; off < 256; off <<= 1) {
        int u = t >= off ? s[t - off] : 0;
        __syncthreads();
        s[t] += u;
        __syncthreads();
    }
    int run = s[t] - sum;
#pragma unroll
    for (int j = 0; j < 4; ++j) {
        if (base + j < n) excl[base + j] = run;
        run += c[j];
    }
    if (t == 255) bsum[blockIdx.x] = s[255];
}
__global__ void k_scan2(int* bsum, int nb) {
    __shared__ int s[1024];
    int t = threadIdx.x;
    int v = t < nb ? bsum[t] : 0;
    s[t] = v;
    __syncthreads();
    for (int off = 1; off < 1024; off <<= 1) {
        int u = t >= off ? s[t - off] : 0;
        __syncthreads();
        s[t] += u;
        __syncthreads();
    }
    if (t < nb) bsum[t] = s[t] - v;
}
__global__ void k_scan3(int* __restrict__ rowst, const int* __restrict__ bsum,
                        int* __restrict__ cursor, int n) {
    int i = blockIdx.x * 256 + threadIdx.x;
    if (i < n) {
        int v = rowst[i] + bsum[i >> 10];
        rowst[i] = v;
        cursor[i] = v;
    }
    if (i == 0) rowst[n] = EE;  // CSR sentinel
}

// --- 5. exp + denom + seg-CSR scatter of packed (src, p)
__global__ void k_edge_b(const int* __restrict__ tri, const float* __restrict__ eraw,
        const unsigned* __restrict__ umax, float* __restrict__ denom,
        int* __restrict__ cursor, int2* __restrict__ pdata) {
    int e = blockIdx.x * 256 + threadIdx.x;
    int src = tri[3 * e], dst = tri[3 * e + 2];
    int rel = e / EPR;
    int seg = rel * NN + dst;
    float p = __expf(eraw[e] - funkey(umax[seg]));
    atomicAdd(&denom[seg], p);
    int pos = atomicAdd(&cursor[seg], 1);
    pdata[pos] = make_int2(src, __float_as_int(p));
}

// --- 6. fused aggregate-in-x-space + GEMM [16 x 1024] @ WT^T + bias + residual.
// Block: 256 thr (4 waves), owns 16 dst rows. A-tile 16x1024 bf16 in LDS (32KB),
// XOR-swizzled (16B granule) against stride-2048B bank conflicts.
__global__ __launch_bounds__(256, 4) void k_fused(const int* __restrict__ rowst,
        const int2* __restrict__ pdata, const float* __restrict__ denom,
        const uint4* __restrict__ xbv, const unsigned short* __restrict__ wtt,
        const float* __restrict__ x, const float* __restrict__ bias,
        float* __restrict__ out) {
    __shared__ unsigned short atile[16 * 1024];  // 32KB, row stride 2048B
    char* ab = (char*)atile;
    int d0 = blockIdx.x * 16;
    int gid = threadIdx.x >> 4;   // 0..15 (16-lane groups)
    int j16 = threadIdx.x & 15;

    // ---- build phase: 8 rounds x 16 groups = 128 segments (16 dst x 8 rel) ----
    for (int q = 0; q < 8; ++q) {
        int sl = q * 16 + gid;     // 0..127
        int dl = sl >> 3, r = sl & 7;
        int seg = r * NN + d0 + dl;
        int start = rowst[seg];
        int c = rowst[seg + 1] - start;
        float invd = 1.f / fmaxf(denom[seg], 1e-8f);
        float a[8];
#pragma unroll
        for (int t = 0; t < 8; ++t) a[t] = 0.f;
        for (int j0 = 0; j0 < c; j0 += 8) {
#pragma unroll
            for (int j = 0; j < 8; ++j) {
                if (j0 + j < c) {  // uniform within the 16-lane group
                    int2 pd = pdata[start + j0 + j];
                    float al = __int_as_float(pd.y) * invd;
                    uint4 w = xbv[(size_t)pd.x * 16 + j16];
                    a[0] = fmaf(al, __uint_as_float(w.x << 16), a[0]);
                    a[1] = fmaf(al, __uint_as_float(w.x & 0xFFFF0000u), a[1]);
                    a[2] = fmaf(al, __uint_as_float(w.y << 16), a[2]);
                    a[3] = fmaf(al, __uint_as_float(w.y & 0xFFFF0000u), a[3]);
                    a[4] = fmaf(al, __uint_as_float(w.z << 16), a[4]);
                    a[5] = fmaf(al, __uint_as_float(w.z & 0xFFFF0000u), a[5]);
                    a[6] = fmaf(al, __uint_as_float(w.w << 16), a[6]);
                    a[7] = fmaf(al, __uint_as_float(w.w & 0xFFFF0000u), a[7]);
                }
            }
        }
        uint4 o;
        o.x = (unsigned)f2bf(a[0]) | ((unsigned)f2bf(a[1]) << 16);
        o.y = (unsigned)f2bf(a[2]) | ((unsigned)f2bf(a[3]) << 16);
        o.z = (unsigned)f2bf(a[4]) | ((unsigned)f2bf(a[5]) << 16);
        o.w = (unsigned)f2bf(a[6]) | ((unsigned)f2bf(a[7]) << 16);
        *(uint4*)(ab + dl * 2048 + (((r * 16 + j16) ^ (dl & 7)) << 4)) = o;
    }
    __syncthreads();

    // ---- GEMM phase: C[16 x 128] = A[16 x 1024] * B[1024 x 128] ----
    // wave owns n-cols [wave*32, wave*32+32). B[k][n] = WT[n][k] from L2.
    int wave = threadIdx.x >> 6, lane = threadIdx.x & 63;
    int m0 = lane & 15;
    int g = lane >> 4;
    int key = m0 & 7;
    f32x4 acc[2];
    acc[0] = (f32x4){0.f, 0.f, 0.f, 0.f};
    acc[1] = (f32x4){0.f, 0.f, 0.f, 0.f};
    const unsigned short* b0p = wtt + (size_t)(wave * 32 + m0) * KK + g * 8;
    const unsigned short* b1p = b0p + (size_t)16 * KK;
#pragma unroll 8
    for (int ks = 0; ks < 32; ++ks) {
        int e16 = ks * 4 + g;
        short8 a0 = *(const short8*)(ab + m0 * 2048 + ((e16 ^ key) << 4));
        short8 b0 = *(const short8*)(b0p + ks * 32);
        short8 b1 = *(const short8*)(b1p + ks * 32);
        acc[0] = __builtin_amdgcn_mfma_f32_16x16x32_bf16(a0, b0, acc[0], 0, 0, 0);
        acc[1] = __builtin_amdgcn_mfma_f32_16x16x32_bf16(a0, b1, acc[1], 0, 0, 0);
    }
    // epilogue: out = acc + x + bias.  C layout: col=lane&15, row=(lane>>4)*4+j
#pragma unroll
    for (int n = 0; n < 2; ++n) {
        int o = wave * 32 + n * 16 + m0;
        float bv = bias[o];
#pragma unroll
        for (int j = 0; j < 4; ++j) {
            int dl = g * 4 + j;
            size_t idx = (size_t)(d0 + dl) * DIM + o;
            out[idx] = acc[n][j] + x[idx] + bv;
        }
    }
}

extern "C" void kernel_launch(void* const* d_in, const int* in_sizes, int n_in,
                              void* d_out, int out_size, void* d_ws, size_t ws_size,
                              hipStream_t stream) {
    const float* x = (const float*)d_in[0];
    const int* tri = (const int*)d_in[1];
    const float* basis = (const float*)d_in[3];
    const float* att = (const float*)d_in[4];
    const float* attention = (const float*)d_in[5];
    const float* bias = (const float*)d_in[6];
    float* out = (float*)d_out;

    char* ws = (char*)d_ws;
    size_t off = 0;
    auto alloc = [&](size_t b) {
        char* p = ws + off;
        off = (off + b + 255) & ~(size_t)255;
        return p;
    };
    unsigned* xb = (unsigned*)alloc((size_t)NN * DIM * 2);              // 25.6 MB
    unsigned short* wtt = (unsigned short*)alloc((size_t)DIM * KK * 2); // 256 KB
    float* wsrc = (float*)alloc(RR * DIM * 4);
    float* wdst = (float*)alloc(RR * DIM * 4);
    float* ssrc = (float*)alloc((size_t)RR * NN * 4);
    float* sdst = (float*)alloc((size_t)RR * NN * 4);
    float* eraw = (float*)alloc((size_t)EE * 4);
    unsigned* umax = (unsigned*)alloc((size_t)RN * 4);
    float* denom = (float*)alloc((size_t)RN * 4);
    int* cnt = (int*)alloc((size_t)RN * 4);
    int* rowst = (int*)alloc((size_t)(RN + 1) * 4);
    int* cursor = (int*)alloc((size_t)RN * 4);
    int* bsum = (int*)alloc(4096);
    int2* pdata = (int2*)alloc((size_t)EE * 8);

    (void)hipMemsetAsync(umax, 0, (size_t)RN * 4, stream);
    (void)hipMemsetAsync(denom, 0, (size_t)RN * 4, stream);
    (void)hipMemsetAsync(cnt, 0, (size_t)RN * 4, stream);

    k_prep<<<RR, DIM, 0, stream>>>(att, basis, attention, wtt, wsrc, wdst);
    k_scores<<<NN / 4, 256, 0, stream>>>(x, wsrc, wdst, ssrc, sdst, xb);
    k_edge_a<<<EE / 256, 256, 0, stream>>>(tri, ssrc, sdst, eraw, umax, cnt);
    int nb = (RN + 1023) / 1024;  // 782
    k_scan1<<<nb, 256, 0, stream>>>(cnt, rowst, bsum, RN);
    k_scan2<<<1, 1024, 0, stream>>>(bsum, nb);
    k_scan3<<<(RN + 255) / 256, 256, 0, stream>>>(rowst, bsum, cursor, RN);
    k_edge_b<<<EE / 256, 256, 0, stream>>>(tri, eraw, umax, denom, cursor, pdata);
    k_fused<<<NN / 16, 256, 0, stream>>>(rowst, pdata, denom,
                                         (const uint4*)xb, wtt, x, bias, out);
}